// Round 6
// baseline (51.039 us; speedup 1.0000x reference)
//
#include <hip/hip_runtime.h>
#include <cmath>

#define NCLS 6
#define GRP 256
#define DIM 256

typedef __attribute__((ext_vector_type(8))) short short8;
typedef __attribute__((ext_vector_type(4))) float f32x4;

__device__ inline unsigned short f2bf(float f) {
    unsigned u = __float_as_uint(f);
    return (unsigned short)((u + 0x7FFFu + ((u >> 16) & 1u)) >> 16);
}

// ---------------- K0: bf16 hi/lo split + row norms + counter zero ----------------
// 384 blocks x 256 thr; wave per row (4 rows/block), lane owns 4 columns.
__global__ __launch_bounds__(256) void prep_kernel(
    const float* __restrict__ feat,
    unsigned short* __restrict__ hi,
    unsigned short* __restrict__ lo,
    float* __restrict__ n2,
    unsigned int* __restrict__ counter)
{
    const int b = blockIdx.x, t = threadIdx.x;
    if (b == 0 && t == 0)
        __hip_atomic_store(counter, 0u, __ATOMIC_RELAXED, __HIP_MEMORY_SCOPE_AGENT);

    const int row = (b << 2) + (t >> 6);
    const int l   = t & 63;
    float4 v = *reinterpret_cast<const float4*>(feat + (size_t)row * DIM + (l << 2));

    unsigned short h[4], w[4];
    float fv[4] = {v.x, v.y, v.z, v.w};
    #pragma unroll
    for (int e = 0; e < 4; ++e) {
        h[e] = f2bf(fv[e]);
        float hf = __uint_as_float((unsigned)h[e] << 16);
        w[e] = f2bf(fv[e] - hf);
    }
    *reinterpret_cast<ushort4*>(hi + (size_t)row * DIM + (l << 2)) =
        make_ushort4(h[0], h[1], h[2], h[3]);
    *reinterpret_cast<ushort4*>(lo + (size_t)row * DIM + (l << 2)) =
        make_ushort4(w[0], w[1], w[2], w[3]);

    float n = fv[0]*fv[0] + fv[1]*fv[1] + fv[2]*fv[2] + fv[3]*fv[3];
    #pragma unroll
    for (int off = 32; off > 0; off >>= 1)
        n += __shfl_xor(n, off);
    if (l == 0) n2[row] = n;
}

// ---------------- K1: per-class Gram via bf16-split MFMA -> lg rows ----------------
// 1536 wave-tiles (6 classes x 16x16 tiles of 16x16); 384 blocks x 4 waves.
// A/B frag (16x16x32 bf16): elem = M[row = lane&15][k = kb*32 + (lane>>4)*8 + e].
// C/D (verified m89): col = lane&15, row = (lane>>4)*4 + reg.
__global__ __launch_bounds__(256) void gram_kernel(
    const unsigned short* __restrict__ hi,
    const unsigned short* __restrict__ lo,
    const float* __restrict__ n2,
    float* __restrict__ lg)            // [1536][256]
{
    const int id   = (blockIdx.x << 2) + (threadIdx.x >> 6);  // wave-tile id
    const int lane = threadIdx.x & 63;
    const int cls  = id >> 8;
    const int rem  = id & 255;
    const int i0   = (cls << 8) + ((rem >> 4) << 4);   // global anchor-row base
    const int jc0  = (rem & 15) << 4;                  // in-class k base
    const int j0   = (cls << 8) + jc0;                 // global k-row base

    const int rsel = lane & 15;
    const int ksub = (lane >> 4) << 3;

    const size_t arow = (size_t)(i0 + rsel) * DIM;
    const size_t brow = (size_t)(j0 + rsel) * DIM;

    f32x4 acc = {0.f, 0.f, 0.f, 0.f};
    #pragma unroll
    for (int kb = 0; kb < 8; ++kb) {
        const int off = (kb << 5) + ksub;
        short8 ah = *reinterpret_cast<const short8*>(hi + arow + off);
        short8 al = *reinterpret_cast<const short8*>(lo + arow + off);
        short8 bh = *reinterpret_cast<const short8*>(hi + brow + off);
        short8 bl = *reinterpret_cast<const short8*>(lo + brow + off);
        acc = __builtin_amdgcn_mfma_f32_16x16x32_bf16(ah, bh, acc, 0, 0, 0);
        acc = __builtin_amdgcn_mfma_f32_16x16x32_bf16(ah, bl, acc, 0, 0, 0);
        acc = __builtin_amdgcn_mfma_f32_16x16x32_bf16(al, bh, acc, 0, 0, 0);
    }

    const float nk    = n2[j0 + rsel];            // col = lane&15
    const int   rbase = i0 + ((lane >> 4) << 2);
    #pragma unroll
    for (int r = 0; r < 4; ++r) {
        float d2 = n2[rbase + r] + nk - 2.f * acc[r];
        float lgv = -0.5f * sqrtf(fmaxf(d2, 0.f) + 1e-12f);
        lg[(size_t)(rbase + r) * GRP + jc0 + rsel] = lgv;
    }
}

// ---------------- K2: labels + denom + log-prob sum + fused finalize ----------------
// 1536 blocks (one per anchor) x 256 threads.
__global__ __launch_bounds__(256) void denom_kernel(
    const float* __restrict__ lg,
    const float* __restrict__ green,
    const float* __restrict__ red,
    const float* __restrict__ trans,
    const int*   __restrict__ sym,
    float* __restrict__ partial,
    unsigned int* __restrict__ counter,
    float* __restrict__ out)
{
    __shared__ __align__(16) float2 LEs[GRP];    // (L, ev)
    __shared__ __align__(16) float pd[GRP][4];   // per-wave denom partials
    __shared__ float rbuf[4];
    __shared__ int iswin;

    const int a    = blockIdx.x;
    const int c    = a >> 8;
    const int i    = a & 255;
    const int base = c << 8;
    const int t    = threadIdx.x;
    const int w    = t >> 6;
    const int l    = t & 63;

    const float lgt = lg[(size_t)a * GRP + t];

    // ---- label distance L(i, t) ----
    {
        const int kg = base + t;
        float l1g = fabsf(green[3*a]   - green[3*kg])
                  + fabsf(green[3*a+1] - green[3*kg+1])
                  + fabsf(green[3*a+2] - green[3*kg+2]);
        float l1t = fabsf(trans[3*a]   - trans[3*kg])
                  + fabsf(trans[3*a+1] - trans[3*kg+1])
                  + fabsf(trans[3*a+2] - trans[3*kg+2]);
        float L;
        if (c < 2) {
            L = 0.8f * l1g + 0.2f * l1t;
        } else {
            float l1r = fabsf(red[3*a]   - red[3*kg])
                      + fabsf(red[3*a+1] - red[3*kg+1])
                      + fabsf(red[3*a+2] - red[3*kg+2]);
            float rot;
            if (c < 5) {
                rot = 0.5f * (l1g + l1r);
            } else {
                float both = ((sym[4*a] == 0) && (sym[4*kg] == 0)) ? 1.f : 0.f;
                rot = (l1g + both * l1r) / (1.f + both);
            }
            L = 0.8f * rot + 0.2f * l1t;
        }
        LEs[t] = make_float2(L, __expf(lgt));
    }
    __syncthreads();

    // ---- denom scan: wave w covers k in [64w, 64w+64), 4 j's per lane ----
    float L0 = LEs[l].x;
    float L1 = LEs[l + 64].x;
    float L2 = LEs[l + 128].x;
    float L3 = LEs[l + 192].x;

    const float4* p4 = reinterpret_cast<const float4*>(LEs);
    float dn0 = 0.f, dn1 = 0.f, dn2 = 0.f, dn3 = 0.f;
    const int q0 = w << 5;
    #pragma unroll 8
    for (int q = q0; q < q0 + 32; ++q) {
        float4 u = p4[q];                 // uniform broadcast: (L,ev) x2
        dn0 += (u.x >= L0) ? u.y : 0.f;  dn0 += (u.z >= L0) ? u.w : 0.f;
        dn1 += (u.x >= L1) ? u.y : 0.f;  dn1 += (u.z >= L1) ? u.w : 0.f;
        dn2 += (u.x >= L2) ? u.y : 0.f;  dn2 += (u.z >= L2) ? u.w : 0.f;
        dn3 += (u.x >= L3) ? u.y : 0.f;  dn3 += (u.z >= L3) ? u.w : 0.f;
    }
    pd[l][w]       = dn0;
    pd[l + 64][w]  = dn1;
    pd[l + 128][w] = dn2;
    pd[l + 192][w] = dn3;
    __syncthreads();

    float4 dns = *reinterpret_cast<const float4*>(pd[t]);
    float dn = (dns.x + dns.y) + (dns.z + dns.w);
    float part = (t != i) ? (lgt - __logf(dn)) : 0.f;

    #pragma unroll
    for (int off = 32; off > 0; off >>= 1)
        part += __shfl_xor(part, off);
    if (l == 0) rbuf[w] = part;
    __syncthreads();
    if (t == 0) {
        float s = (rbuf[0] + rbuf[1]) + (rbuf[2] + rbuf[3]);
        __hip_atomic_store(&partial[a], s, __ATOMIC_RELAXED, __HIP_MEMORY_SCOPE_AGENT);
        unsigned int old = __hip_atomic_fetch_add(counter, 1u, __ATOMIC_ACQ_REL,
                                                  __HIP_MEMORY_SCOPE_AGENT);
        iswin = (old == NCLS * GRP - 1) ? 1 : 0;
    }
    __syncthreads();

    // ---- last block: deterministic final reduction over 1536 partials ----
    if (iswin) {
        float acc = 0.f;
        for (int k = t; k < NCLS * GRP; k += 256)
            acc += __hip_atomic_load(&partial[k], __ATOMIC_RELAXED,
                                     __HIP_MEMORY_SCOPE_AGENT);
        #pragma unroll
        for (int off = 32; off > 0; off >>= 1)
            acc += __shfl_xor(acc, off);
        if (l == 0) rbuf[w] = acc;
        __syncthreads();
        if (t == 0) {
            float s = (rbuf[0] + rbuf[1]) + (rbuf[2] + rbuf[3]);
            out[0] = -s / (256.f * 255.f * 6.f);
        }
    }
}

extern "C" void kernel_launch(void* const* d_in, const int* in_sizes, int n_in,
                              void* d_out, int out_size, void* d_ws, size_t ws_size,
                              hipStream_t stream)
{
    const float* feat  = (const float*)d_in[0];
    // d_in[1] = labels: unused (classes are contiguous GROUP-sized slices)
    const float* green = (const float*)d_in[2];
    const float* red   = (const float*)d_in[3];
    const float* trans = (const float*)d_in[4];
    const int*   sym   = (const int*)d_in[5];

    float* wsf = (float*)d_ws;
    float*          partial = wsf;                                   // 1536 f32
    unsigned int*   counter = (unsigned int*)(wsf + 1600);           // 1 u32
    float*          n2      = wsf + 2048;                            // 1536 f32
    float*          lg      = wsf + 4096;                            // 1536*256 f32
    unsigned short* hi      = (unsigned short*)(wsf + 4096 + NCLS * GRP * DIM);
    unsigned short* lo      = hi + (size_t)NCLS * GRP * DIM;
    float* out = (float*)d_out;

    prep_kernel <<<NCLS * GRP / 4, 256, 0, stream>>>(feat, hi, lo, n2, counter);
    gram_kernel <<<NCLS * GRP * GRP / (16 * 16) / 4, 256, 0, stream>>>(hi, lo, n2, lg);
    denom_kernel<<<NCLS * GRP, 256, 0, stream>>>(lg, green, red, trans, sym,
                                                 partial, counter, out);
}

// Round 7
// 46.860 us; speedup vs baseline: 1.0892x; 1.0892x over previous
//
#include <hip/hip_runtime.h>
#include <cmath>

#define NCLS 6
#define GRP 256
#define DIM 256

typedef __attribute__((ext_vector_type(8))) short short8;
typedef __attribute__((ext_vector_type(4))) float f32x4;

__device__ inline unsigned short f2bf(float f) {
    unsigned u = __float_as_uint(f);
    return (unsigned short)((u + 0x7FFFu + ((u >> 16) & 1u)) >> 16);
}

// ---------------- K0: bf16 hi/lo split into MFMA fragment layout + row norms ----
// Fragment layout: frag[(tileIdx*8 + kb)*64 + lane][e], tileIdx = cls*16 + tile.
// Lane l of fragment (tile, kb) holds row tile*16 + (l&15), k = kb*32 + (l>>4)*8 + e.
// Grid: 96 blocks (one per 16-row tile) x 256 threads.
__global__ __launch_bounds__(256) void prep_kernel(
    const float* __restrict__ feat,
    unsigned short* __restrict__ hifrag,
    unsigned short* __restrict__ lofrag,
    float* __restrict__ n2,
    unsigned int* __restrict__ counter)
{
    __shared__ float n2p[16][17];
    const int b = blockIdx.x;                 // b = cls*16 + tile
    const int t = threadIdx.x;
    if (b == 0 && t == 0)
        __hip_atomic_store(counter, 0u, __ATOMIC_RELAXED, __HIP_MEMORY_SCOPE_AGENT);

    const int rowbase = ((b >> 4) << 8) + ((b & 15) << 4);   // cls*256 + tile*16

    #pragma unroll
    for (int pi = 0; pi < 2; ++pi) {
        const int p    = t + (pi << 8);       // fragment position: p = kb*64 + lane
        const int kb   = p >> 6;
        const int lane = p & 63;
        const int row  = rowbase + (lane & 15);
        const int k0   = (kb << 5) + ((lane >> 4) << 3);

        const float* src = feat + (size_t)row * DIM + k0;
        float4 v0 = *reinterpret_cast<const float4*>(src);
        float4 v1 = *reinterpret_cast<const float4*>(src + 4);
        float fv[8] = {v0.x, v0.y, v0.z, v0.w, v1.x, v1.y, v1.z, v1.w};

        short8 h, lo;
        #pragma unroll
        for (int e = 0; e < 8; ++e) {
            unsigned short hb = f2bf(fv[e]);
            float hf = __uint_as_float((unsigned)hb << 16);
            h[e]  = (short)hb;
            lo[e] = (short)f2bf(fv[e] - hf);
        }
        const size_t fidx = ((size_t)(b * 8 + kb) * 64 + lane) * 8;
        *reinterpret_cast<short8*>(hifrag + fidx) = h;    // coalesced 16B/lane
        *reinterpret_cast<short8*>(lofrag + fidx) = lo;
    }

    // ---- exact f32 row norms ----
    {
        const int r16 = t >> 4, chunk = t & 15;
        const float* src = feat + (size_t)(rowbase + r16) * DIM + (chunk << 4);
        float s = 0.f;
        #pragma unroll
        for (int q = 0; q < 4; ++q) {
            float4 v = *reinterpret_cast<const float4*>(src + (q << 2));
            s += v.x * v.x + v.y * v.y + v.z * v.z + v.w * v.w;
        }
        n2p[r16][chunk] = s;
    }
    __syncthreads();
    if (t < 16) {
        float s = 0.f;
        #pragma unroll
        for (int q = 0; q < 16; ++q) s += n2p[t][q];
        n2[rowbase + t] = s;
    }
}

// ---------------- K1: per-class Gram via bf16-split MFMA -> lg ----------------
// Grid: 384 blocks (cls, i-tile, k-quarter) x 512 threads (8 waves).
// Wave w: j-tile = kq*4 + (w>>1), kb-half = w&1. All operand loads coalesced 1KB.
// C/D mapping (verified, m89 + R6 pass): col = lane&15 (j), row = (lane>>4)*4+reg (i).
__global__ __launch_bounds__(512) void gram_kernel(
    const unsigned short* __restrict__ hifrag,
    const unsigned short* __restrict__ lofrag,
    const float* __restrict__ n2,
    float* __restrict__ lg)            // [1536][256]
{
    __shared__ __align__(16) f32x4 accb[4][64];

    const int b    = blockIdx.x;
    const int cls  = b >> 6;
    const int it   = (b >> 2) & 15;
    const int kq   = b & 3;
    const int t    = threadIdx.x;
    const int w    = t >> 6;
    const int lane = t & 63;
    const int jt   = (kq << 2) + (w >> 1);
    const int kbh  = w & 1;

    const int tA = (cls << 4) + it;
    const int tB = (cls << 4) + jt;

    f32x4 acc = {0.f, 0.f, 0.f, 0.f};
    #pragma unroll
    for (int kk = 0; kk < 4; ++kk) {
        const int kb = (kbh << 2) + kk;
        const size_t ia = ((size_t)(tA * 8 + kb) * 64 + lane) * 8;
        const size_t ib = ((size_t)(tB * 8 + kb) * 64 + lane) * 8;
        short8 ah = *reinterpret_cast<const short8*>(hifrag + ia);
        short8 al = *reinterpret_cast<const short8*>(lofrag + ia);
        short8 bh = *reinterpret_cast<const short8*>(hifrag + ib);
        short8 bl = *reinterpret_cast<const short8*>(lofrag + ib);
        acc = __builtin_amdgcn_mfma_f32_16x16x32_bf16(ah, bh, acc, 0, 0, 0);
        acc = __builtin_amdgcn_mfma_f32_16x16x32_bf16(ah, bl, acc, 0, 0, 0);
        acc = __builtin_amdgcn_mfma_f32_16x16x32_bf16(al, bh, acc, 0, 0, 0);
    }

    if (kbh == 1) accb[w >> 1][lane] = acc;
    __syncthreads();
    if (kbh == 0) {
        f32x4 o = accb[w >> 1][lane];
        const int   col   = lane & 15;
        const float nj    = n2[(cls << 8) + (jt << 4) + col];
        const int   rbase = (cls << 8) + (it << 4) + ((lane >> 4) << 2);
        #pragma unroll
        for (int r = 0; r < 4; ++r) {
            float g  = acc[r] + o[r];
            float d2 = n2[rbase + r] + nj - 2.f * g;
            float lgv = -0.5f * sqrtf(fmaxf(d2, 0.f) + 1e-12f);
            lg[(size_t)(rbase + r) * GRP + (jt << 4) + col] = lgv;
        }
    }
}

// ---------------- K2: labels + denom + log-prob sum + fused finalize ----------------
// 1536 blocks (one per anchor) x 256 threads.
__global__ __launch_bounds__(256) void denom_kernel(
    const float* __restrict__ lg,
    const float* __restrict__ green,
    const float* __restrict__ red,
    const float* __restrict__ trans,
    const int*   __restrict__ sym,
    float* __restrict__ partial,
    unsigned int* __restrict__ counter,
    float* __restrict__ out)
{
    __shared__ __align__(16) float2 LEs[GRP];    // (L, ev)
    __shared__ __align__(16) float pd[GRP][4];   // per-wave denom partials
    __shared__ float rbuf[4];
    __shared__ int iswin;

    const int a    = blockIdx.x;
    const int c    = a >> 8;
    const int i    = a & 255;
    const int base = c << 8;
    const int t    = threadIdx.x;
    const int w    = t >> 6;
    const int l    = t & 63;

    const float lgt = lg[(size_t)a * GRP + t];

    // ---- label distance L(i, t) ----
    {
        const int kg = base + t;
        float l1g = fabsf(green[3*a]   - green[3*kg])
                  + fabsf(green[3*a+1] - green[3*kg+1])
                  + fabsf(green[3*a+2] - green[3*kg+2]);
        float l1t = fabsf(trans[3*a]   - trans[3*kg])
                  + fabsf(trans[3*a+1] - trans[3*kg+1])
                  + fabsf(trans[3*a+2] - trans[3*kg+2]);
        float L;
        if (c < 2) {
            L = 0.8f * l1g + 0.2f * l1t;
        } else {
            float l1r = fabsf(red[3*a]   - red[3*kg])
                      + fabsf(red[3*a+1] - red[3*kg+1])
                      + fabsf(red[3*a+2] - red[3*kg+2]);
            float rot;
            if (c < 5) {
                rot = 0.5f * (l1g + l1r);
            } else {
                float both = ((sym[4*a] == 0) && (sym[4*kg] == 0)) ? 1.f : 0.f;
                rot = (l1g + both * l1r) / (1.f + both);
            }
            L = 0.8f * rot + 0.2f * l1t;
        }
        LEs[t] = make_float2(L, __expf(lgt));
    }
    __syncthreads();

    // ---- denom scan: wave w covers k in [64w, 64w+64), 4 j's per lane ----
    float L0 = LEs[l].x;
    float L1 = LEs[l + 64].x;
    float L2 = LEs[l + 128].x;
    float L3 = LEs[l + 192].x;

    const float4* p4 = reinterpret_cast<const float4*>(LEs);
    float dn0 = 0.f, dn1 = 0.f, dn2 = 0.f, dn3 = 0.f;
    const int q0 = w << 5;
    #pragma unroll 8
    for (int q = q0; q < q0 + 32; ++q) {
        float4 u = p4[q];                 // uniform broadcast: (L,ev) x2
        dn0 += (u.x >= L0) ? u.y : 0.f;  dn0 += (u.z >= L0) ? u.w : 0.f;
        dn1 += (u.x >= L1) ? u.y : 0.f;  dn1 += (u.z >= L1) ? u.w : 0.f;
        dn2 += (u.x >= L2) ? u.y : 0.f;  dn2 += (u.z >= L2) ? u.w : 0.f;
        dn3 += (u.x >= L3) ? u.y : 0.f;  dn3 += (u.z >= L3) ? u.w : 0.f;
    }
    pd[l][w]       = dn0;
    pd[l + 64][w]  = dn1;
    pd[l + 128][w] = dn2;
    pd[l + 192][w] = dn3;
    __syncthreads();

    float4 dns = *reinterpret_cast<const float4*>(pd[t]);
    float dn = (dns.x + dns.y) + (dns.z + dns.w);
    float part = (t != i) ? (lgt - __logf(dn)) : 0.f;

    #pragma unroll
    for (int off = 32; off > 0; off >>= 1)
        part += __shfl_xor(part, off);
    if (l == 0) rbuf[w] = part;
    __syncthreads();
    if (t == 0) {
        float s = (rbuf[0] + rbuf[1]) + (rbuf[2] + rbuf[3]);
        __hip_atomic_store(&partial[a], s, __ATOMIC_RELAXED, __HIP_MEMORY_SCOPE_AGENT);
        unsigned int old = __hip_atomic_fetch_add(counter, 1u, __ATOMIC_ACQ_REL,
                                                  __HIP_MEMORY_SCOPE_AGENT);
        iswin = (old == NCLS * GRP - 1) ? 1 : 0;
    }
    __syncthreads();

    // ---- last block: deterministic final reduction over 1536 partials ----
    if (iswin) {
        float acc = 0.f;
        for (int k = t; k < NCLS * GRP; k += 256)
            acc += __hip_atomic_load(&partial[k], __ATOMIC_RELAXED,
                                     __HIP_MEMORY_SCOPE_AGENT);
        #pragma unroll
        for (int off = 32; off > 0; off >>= 1)
            acc += __shfl_xor(acc, off);
        if (l == 0) rbuf[w] = acc;
        __syncthreads();
        if (t == 0) {
            float s = (rbuf[0] + rbuf[1]) + (rbuf[2] + rbuf[3]);
            out[0] = -s / (256.f * 255.f * 6.f);
        }
    }
}

extern "C" void kernel_launch(void* const* d_in, const int* in_sizes, int n_in,
                              void* d_out, int out_size, void* d_ws, size_t ws_size,
                              hipStream_t stream)
{
    const float* feat  = (const float*)d_in[0];
    // d_in[1] = labels: unused (classes are contiguous GROUP-sized slices)
    const float* green = (const float*)d_in[2];
    const float* red   = (const float*)d_in[3];
    const float* trans = (const float*)d_in[4];
    const int*   sym   = (const int*)d_in[5];

    float* wsf = (float*)d_ws;
    float*          partial = wsf;                          // 1536 f32
    unsigned int*   counter = (unsigned int*)(wsf + 1600);  // 1 u32
    float*          n2      = wsf + 2048;                   // 1536 f32
    float*          lg      = wsf + 4096;                   // 393216 f32
    unsigned short* hifrag  = (unsigned short*)(wsf + 4096 + NCLS * GRP * DIM);
    unsigned short* lofrag  = hifrag + (size_t)NCLS * GRP * DIM;
    float* out = (float*)d_out;

    prep_kernel <<<NCLS * 16, 256, 0, stream>>>(feat, hifrag, lofrag, n2, counter);
    gram_kernel <<<NCLS * 16 * 4, 512, 0, stream>>>(hifrag, lofrag, n2, lg);
    denom_kernel<<<NCLS * GRP, 256, 0, stream>>>(lg, green, red, trans, sym,
                                                 partial, counter, out);
}